// Round 3
// baseline (872.623 us; speedup 1.0000x reference)
//
#include <hip/hip_runtime.h>
#include <hip/hip_bf16.h>

// RGCN layer, MI355X — round 14.
// r13 post-mortem: fused conv correct but 588us, MfmaUtil 1.8% — pure latency.
// Per-rel serial chain: ssd-load -> gather -> vmcnt(0) drain -> barrier with
// no overlap; 40690 tile-iterations at ~7us each / ~2 in flight per CU.
// FIX: (1) bulk-preload the block's contiguous ssd range into LDS (kills the
// dependent ssd->gather hop); (2) register-prefetch A(16 VGPR)+W(16 VGPR)+norm
// for rel r+1 DURING the GEMM of rel r (T14 async-split), ds_write after the
// barrier with the XOR swizzle applied on the LDS address (same layout as
// r13's source-swizzled async16); (3) LDS 53.1KB -> 3 blocks/CU.
// Scatter/combine/bn/resid and all index math identical to the passing r13.

#define N_NODES 20000
#define E_EDGES 640000
#define R_REL   65
#define NGRP    313                 // ceil(20000/64)
#define NKEY    (NGRP * R_REL)      // 20345
#define NB_CONV (NGRP * 4)          // (g, colhalf, relhalf) = 1252
#define NB_RES  (NGRP * 2)          // (rowgrp, colhalf)     = 626
#define CAP_SIDX 1088

typedef __attribute__((ext_vector_type(8))) short bf16x8;
typedef __attribute__((ext_vector_type(4))) float f32x4;
typedef __attribute__((ext_vector_type(4))) unsigned int u32x4;
typedef __attribute__((ext_vector_type(2))) unsigned int u32x2;

__device__ __forceinline__ unsigned short f2bf(float x) {
    union { float f; unsigned int u; } c; c.f = x;
    unsigned int b = c.u + 0x7fffu + ((c.u >> 16) & 1u);   // RTNE
    return (unsigned short)(b >> 16);
}
__device__ __forceinline__ void async16(const void* g, void* l) {
    __builtin_amdgcn_global_load_lds(
        (const __attribute__((address_space(1))) unsigned int*)g,
        (__attribute__((address_space(3))) unsigned int*)l, 16, 0, 0);
}

// ---------------- K1: basis GEMM || key histogram || f32->bf16 cvt ---------
__global__ void k_prep1(const float* __restrict__ comp, const float* __restrict__ basis,
                        float* __restrict__ W32, const int* __restrict__ et,
                        const int* __restrict__ dstA, int* __restrict__ gh3,
                        const float* __restrict__ node_feats,
                        unsigned short* __restrict__ node_bf) {
    __shared__ float lc[16 * 65];
    int b = blockIdx.x, t = threadIdx.x;
    if (b < 320) {                                  // basis GEMM: W32 = comp @ basis
        int r0 = (b >> 6) * 16;
        int col = (b & 63) * 256 + t;
        for (int j = t; j < 16 * 65; j += 256) {
            int rr = r0 + j / 65;
            lc[j] = (rr < R_REL) ? comp[rr * 65 + (j % 65)] : 0.f;
        }
        __syncthreads();
        float acc[16];
#pragma unroll
        for (int j = 0; j < 16; ++j) acc[j] = 0.f;
        for (int k = 0; k < 65; ++k) {
            float v = basis[k * 16384 + col];
#pragma unroll
            for (int j = 0; j < 16; ++j) acc[j] += lc[j * 65 + k] * v;
        }
#pragma unroll
        for (int j = 0; j < 16; ++j) {
            int rr = r0 + j;
            if (rr < R_REL) W32[rr * 16384 + col] = acc[j];
        }
    } else if (b < 832) {                           // per-(dstgrp,rel) histogram
        for (int i = (b - 320) * 256 + t; i < E_EDGES; i += 512 * 256)
            atomicAdd(&gh3[(dstA[i] >> 6) * 65 + et[i]], 1);
    } else {                                        // cvt fp32 -> bf16 (x4)
        int i = (b - 832) * 256 + t;
        if (i < N_NODES * 32) {
            float4 v = reinterpret_cast<const float4*>(node_feats)[i];
            __hip_bfloat162 b0 = __float22bfloat162_rn(make_float2(v.x, v.y));
            __hip_bfloat162 b1 = __float22bfloat162_rn(make_float2(v.z, v.w));
            u32x2 pk;
            pk.x = *reinterpret_cast<unsigned int*>(&b0);
            pk.y = *reinterpret_cast<unsigned int*>(&b1);
            reinterpret_cast<u32x2*>(node_bf)[i] = pk;
        }
    }
}

// ---------------- K2: key scan (self prefix) || W transposes ---------------
__global__ void k_prep2(const int* __restrict__ gh3, int* __restrict__ segK,
                        int* __restrict__ cnt3, const float* __restrict__ W32,
                        unsigned short* __restrict__ Wt, const float* __restrict__ Wresf,
                        unsigned short* __restrict__ Wrest) {
    int b = blockIdx.x, t = threadIdx.x;
    if (b < 80) {                                   // scan 20345 keys
        __shared__ int red[256];
        __shared__ int pref;
        int acc = 0;
        for (int i = t; i < b * 256; i += 256) acc += gh3[i];
        red[t] = acc;
        __syncthreads();
        for (int off = 128; off > 0; off >>= 1) {
            if (t < off) red[t] += red[t + off];
            __syncthreads();
        }
        if (t == 0) pref = red[0];
        __syncthreads();
        int i = b * 256 + t;
        int v = (i < NKEY) ? gh3[i] : 0;
        red[t] = v;
        __syncthreads();
        for (int off = 1; off < 256; off <<= 1) {
            int x = (t >= off) ? red[t - off] : 0;
            __syncthreads();
            red[t] += x;
            __syncthreads();
        }
        int excl = red[t] - v + pref;
        if (i < NKEY) {
            segK[i] = excl;
            cnt3[i] = excl;
            if (i == NKEY - 1) segK[NKEY] = excl + v;
        }
    } else {                                        // transposes (264 blocks)
        __shared__ float tile[64][65];
        int bb = b - 80;
        const float* s; unsigned short* d; int sub;
        if (bb < R_REL * 4) { s = W32 + (size_t)(bb >> 2) * 16384; d = Wt + (size_t)(bb >> 2) * 16384; sub = bb & 3; }
        else { s = Wresf; d = Wrest; sub = bb - R_REL * 4; }
        int ot = (sub >> 1) & 1, itl = sub & 1;
        int tx = t & 63, ty = t >> 6;
        for (int it = 0; it < 16; ++it) {
            int i = ty + it * 4;
            tile[i][tx] = s[(itl * 64 + i) * 128 + ot * 64 + tx];
        }
        __syncthreads();
        for (int it = 0; it < 16; ++it) {
            int o = ty + it * 4;
            d[(ot * 64 + o) * 128 + itl * 64 + tx] = f2bf(tile[tx][o]);
        }
    }
}

// ---------------- K3: bucket scatter (one edge per thread) -----------------
__global__ void k_scatter(const int* __restrict__ et, const int* __restrict__ srcA,
                          const int* __restrict__ dstA, const float* __restrict__ norm,
                          int* __restrict__ cnt3, int* __restrict__ ssd,
                          float* __restrict__ normd) {
    int i = blockIdx.x * 256 + threadIdx.x;
    if (i >= E_EDGES) return;
    int d = dstA[i];
    int key = (d >> 6) * 65 + et[i];
    int p = atomicAdd(&cnt3[key], 1);
    ssd[p] = srcA[i] | ((d & 63) << 15);            // src 15b | slot 6b
    normd[p] = norm[i];
}

// ---------------- K4: fused conv (pipelined, LDS-accumulated) + resid ------
__global__ __launch_bounds__(256, 3) void k_fused(
    const int* __restrict__ segK, const int* __restrict__ ssd,
    const float* __restrict__ normd, const unsigned short* __restrict__ node_bf,
    const unsigned short* __restrict__ Wt, const unsigned short* __restrict__ Wrest,
    const float* __restrict__ b_res, float* __restrict__ hp0,
    float* __restrict__ hp1, float* __restrict__ resid) {
    __shared__ unsigned short Alds[64 * 128];       // 16 KB
    __shared__ unsigned short Blds[64 * 128];       // 16 KB (W col-half)
    __shared__ float hloc[64][65];                  // 16.64 KB f32 accumulator
    __shared__ int sidx[CAP_SIDX];                  // 4.25 KB edge list cache
    __shared__ float snorm[64];
    __shared__ int sslot[64];
    __shared__ int sseg[34];
    int t = threadIdx.x;
    int w = t >> 6, lane = t & 63;
    int lrow = lane & 15, quad = lane >> 4;
    int wc = (w >> 1) * 32;                         // col offset in 64-col half
    int rbase = (w & 1) * 16;                       // row offset in 32-row pass

    if (blockIdx.x >= NB_CONV) {
        // ---- residual tile: relu(x @ W_res[:,ch*64:+64] + b) -> resid
        int rb = blockIdx.x - NB_CONV;
        int row0 = (rb >> 1) * 64, ch = rb & 1;
        int nrows = min(64, N_NODES - row0);
#pragma unroll
        for (int it = 0; it < 4; ++it) {
            int j = t + 256 * it;
            int o = j >> 4, c = j & 15, cs = c ^ (o & 15);
            async16(Wrest + (size_t)(ch * 64 + o) * 128 + cs * 8, &Blds[o * 128 + c * 8]);
        }
#pragma unroll
        for (int it = 0; it < 4; ++it) {
            int j = t + 256 * it;
            int p = j >> 4, c = j & 15, cs = c ^ (p & 15);
            if (p < nrows)
                async16(node_bf + (size_t)(row0 + p) * 128 + cs * 8, &Alds[p * 128 + c * 8]);
        }
        float bb0 = b_res[ch * 64 + wc + lrow];
        float bb1 = b_res[ch * 64 + wc + 16 + lrow];
        __syncthreads();
#pragma unroll
        for (int pass = 0; pass < 2; ++pass) {
            int r0 = pass * 32 + rbase;
            if (r0 >= nrows) break;
            f32x4 acc0 = {0.f, 0.f, 0.f, 0.f}, acc1 = {0.f, 0.f, 0.f, 0.f};
#pragma unroll
            for (int ks = 0; ks < 4; ++ks) {
                int cs = (ks * 4 + quad) ^ lrow;
                bf16x8 a  = *reinterpret_cast<const bf16x8*>(&Alds[(r0 + lrow) * 128 + cs * 8]);
                bf16x8 b0 = *reinterpret_cast<const bf16x8*>(&Blds[(wc + lrow) * 128 + cs * 8]);
                bf16x8 b1 = *reinterpret_cast<const bf16x8*>(&Blds[(wc + 16 + lrow) * 128 + cs * 8]);
                acc0 = __builtin_amdgcn_mfma_f32_16x16x32_bf16(a, b0, acc0, 0, 0, 0);
                acc1 = __builtin_amdgcn_mfma_f32_16x16x32_bf16(a, b1, acc1, 0, 0, 0);
            }
#pragma unroll
            for (int reg = 0; reg < 4; ++reg) {
                int row = r0 + quad * 4 + reg;
                if (row < nrows) {
                    float* rp = resid + (size_t)(row0 + row) * 128 + ch * 64;
                    rp[wc + lrow]      = fmaxf(acc0[reg] + bb0, 0.f);
                    rp[wc + 16 + lrow] = fmaxf(acc1[reg] + bb1, 0.f);
                }
            }
        }
        return;
    }

    // ---- conv block: (group g, col-half ch, rel-half rh)
    int g = blockIdx.x >> 2;
    int ch = (blockIdx.x >> 1) & 1, rh = blockIdx.x & 1;
    int nrel = rh ? 32 : 33;
    int key0 = g * 65 + rh * 33;
    if (t <= nrel) sseg[t] = segK[key0 + t];
    for (int i = t; i < 64 * 65; i += 256) (&hloc[0][0])[i] = 0.f;
    __syncthreads();
    int base0 = sseg[0];
    int capEff = min(sseg[nrel] - base0, CAP_SIDX);
    for (int i = t; i < capEff; i += 256) sidx[i] = ssd[base0 + i];
    __syncthreads();

    int chunk = t & 15;                 // fixed 16B chunk per thread
    int rbase4 = t >> 4;                // row base (0..15), rows at +16*it
    u32x4 pa[4], pw[4];
    int pk4[4];
    float pn4[4];

    auto prefetch = [&](int j) {
        int bR = sseg[j];
        int rowsN = min(64, sseg[j + 1] - bR);
        int r = rh * 33 + j;
        const unsigned short* wbase = Wt + (size_t)r * 16384 + (size_t)ch * 64 * 128;
#pragma unroll
        for (int it = 0; it < 4; ++it) {
            int row = it * 16 + rbase4;
            pw[it] = *reinterpret_cast<const u32x4*>(wbase + row * 128 + chunk * 8);
            if (row < rowsN) {
                int pos = bR - base0 + row;
                int pk = (pos < capEff) ? sidx[pos] : ssd[base0 + pos];
                pk4[it] = pk;
                pa[it] = *reinterpret_cast<const u32x4*>(
                    node_bf + (size_t)(pk & 0x7fff) * 128 + chunk * 8);
                if (chunk == 0) pn4[it] = normd[bR + row];
            }
        }
    };

    auto gemm_epi = [&](int rows) {
#pragma unroll
        for (int pass = 0; pass < 2; ++pass) {
            int r0 = pass * 32 + rbase;
            if (r0 >= rows) break;
            f32x4 acc0 = {0.f, 0.f, 0.f, 0.f}, acc1 = {0.f, 0.f, 0.f, 0.f};
#pragma unroll
            for (int ks = 0; ks < 4; ++ks) {
                int cs = (ks * 4 + quad) ^ lrow;
                bf16x8 a  = *reinterpret_cast<const bf16x8*>(&Alds[(r0 + lrow) * 128 + cs * 8]);
                bf16x8 b0 = *reinterpret_cast<const bf16x8*>(&Blds[(wc + lrow) * 128 + cs * 8]);
                bf16x8 b1 = *reinterpret_cast<const bf16x8*>(&Blds[(wc + 16 + lrow) * 128 + cs * 8]);
                acc0 = __builtin_amdgcn_mfma_f32_16x16x32_bf16(a, b0, acc0, 0, 0, 0);
                acc1 = __builtin_amdgcn_mfma_f32_16x16x32_bf16(a, b1, acc1, 0, 0, 0);
            }
#pragma unroll
            for (int reg = 0; reg < 4; ++reg) {
                int row = r0 + quad * 4 + reg;
                if (row < rows) {
                    float nm = snorm[row];
                    int sl = sslot[row];
                    atomicAdd(&hloc[sl][wc + lrow],      acc0[reg] * nm);
                    atomicAdd(&hloc[sl][wc + 16 + lrow], acc1[reg] * nm);
                }
            }
        }
    };

    prefetch(0);
    for (int rr = 0; rr < nrel; ++rr) {
        int baseR = sseg[rr];
        int cnt = sseg[rr + 1] - baseR;
        int rows0 = min(64, cnt);
        __syncthreads();                 // prior GEMM's LDS reads complete
        // ds_write the prefetched tile (swizzle applied on LDS address)
#pragma unroll
        for (int it = 0; it < 4; ++it) {
            int row = it * 16 + rbase4;
            int sw = (chunk ^ (row & 15)) * 8;
            *reinterpret_cast<u32x4*>(&Blds[row * 128 + sw]) = pw[it];
            if (row < rows0) {
                *reinterpret_cast<u32x4*>(&Alds[row * 128 + sw]) = pa[it];
                if (chunk == 0) { snorm[row] = pn4[it]; sslot[row] = pk4[it] >> 15; }
            }
        }
        __syncthreads();
        if (rr + 1 < nrel) prefetch(rr + 1);   // hide next-rel gathers under GEMM
        gemm_epi(rows0);
        for (int t0 = 64; t0 < cnt; t0 += 64) {    // rare overflow sub-tiles
            int rows = min(64, cnt - t0);
            __syncthreads();
#pragma unroll
            for (int it2 = 0; it2 < 4; ++it2) {
                int j = t + 256 * it2;
                int p = j >> 4, c = j & 15, cs = c ^ (p & 15);
                if (p < rows) {
                    int pk = ssd[baseR + t0 + p];
                    async16(node_bf + (size_t)(pk & 0x7fff) * 128 + cs * 8,
                            &Alds[p * 128 + c * 8]);
                }
            }
            if (t < rows) {
                int pk = ssd[baseR + t0 + t];
                sslot[t] = pk >> 15;
                snorm[t] = normd[baseR + t0 + t];
            }
            __syncthreads();
            gemm_epi(rows);
        }
    }
    __syncthreads();
    float* hp = rh ? hp1 : hp0;
#pragma unroll
    for (int it = 0; it < 16; ++it) {
        int idx = t + 256 * it;
        int sl = idx >> 6, c = idx & 63;
        int node = g * 64 + sl;
        if (node < N_NODES) hp[(size_t)node * 128 + ch * 64 + c] = hloc[sl][c];
    }
}

// ---------------- K5: combine partials + relu + resid + BN stats -----------
__global__ __launch_bounds__(256) void k_combine(
    const float* __restrict__ hp0, const float* __restrict__ hp1,
    const float* __restrict__ resid, const float* __restrict__ h_bias,
    float* __restrict__ h, float* __restrict__ colsum, float* __restrict__ colsumsq) {
    __shared__ float cs1[128], cs2[128], sbias[128];
    int t = threadIdx.x;
    if (t < 128) { cs1[t] = 0.f; cs2[t] = 0.f; sbias[t] = h_bias[t]; }
    __syncthreads();
    int c4 = (t & 31) * 4;
#pragma unroll
    for (int pass = 0; pass < 2; ++pass) {
        int row = blockIdx.x * 16 + pass * 8 + (t >> 5);
        size_t off = (size_t)row * 128 + c4;
        f32x4 va = *reinterpret_cast<const f32x4*>(hp0 + off);
        f32x4 vb = *reinterpret_cast<const f32x4*>(hp1 + off);
        f32x4 vr = *reinterpret_cast<const f32x4*>(resid + off);
        f32x4 v;
#pragma unroll
        for (int k = 0; k < 4; ++k)
            v[k] = fmaxf(va[k] + vb[k] + sbias[c4 + k], 0.f) + vr[k];
        *reinterpret_cast<f32x4*>(h + off) = v;
#pragma unroll
        for (int k = 0; k < 4; ++k) {
            atomicAdd(&cs1[c4 + k], v[k]);
            atomicAdd(&cs2[c4 + k], v[k] * v[k]);
        }
    }
    __syncthreads();
    if (t < 128) {
        atomicAdd(&colsum[t], cs1[t]);
        atomicAdd(&colsumsq[t], cs2[t]);
    }
}

// ---------------- K6: BN apply (natural cols, pure elementwise) ------------
__global__ void k_bn(float* __restrict__ h, const float* __restrict__ colsum,
                     const float* __restrict__ colsumsq, const float* __restrict__ gamma,
                     const float* __restrict__ beta) {
    __shared__ float sc[128], sh2[128];
    int t = threadIdx.x;
    if (t < 128) {
        float m = colsum[t] * (1.f / N_NODES);
        float var = colsumsq[t] * (1.f / N_NODES) - m * m;
        float s = gamma[t] * rsqrtf(var + 1e-5f);
        sc[t] = s;
        sh2[t] = beta[t] - m * s;
    }
    __syncthreads();
    int i = blockIdx.x * 256 + t;                   // one f32x4 per thread
    if (i < N_NODES * 32) {
        int row = i >> 5, c4 = (i & 31) * 4;
        f32x4 v = *reinterpret_cast<f32x4*>(h + (size_t)row * 128 + c4);
#pragma unroll
        for (int k = 0; k < 4; ++k) v[k] = v[k] * sc[c4 + k] + sh2[c4 + k];
        *reinterpret_cast<f32x4*>(h + (size_t)row * 128 + c4) = v;
    }
}

extern "C" void kernel_launch(void* const* d_in, const int* in_sizes, int n_in,
                              void* d_out, int out_size, void* d_ws, size_t ws_size,
                              hipStream_t stream) {
    (void)in_sizes; (void)n_in; (void)out_size; (void)ws_size;
    const float* node_feats = (const float*)d_in[0];
    const int* src    = (const int*)d_in[1];
    const int* dst    = (const int*)d_in[2];
    const int* etype  = (const int*)d_in[3];
    const float* norm = (const float*)d_in[4];
    const float* basis = (const float*)d_in[5];
    const float* comp  = (const float*)d_in[6];
    const float* h_bias = (const float*)d_in[7];
    const float* W_res  = (const float*)d_in[8];
    const float* b_res  = (const float*)d_in[9];
    const float* gamma  = (const float*)d_in[10];
    const float* beta   = (const float*)d_in[11];

    char* ws = (char*)d_ws;
    float* colsum   = (float*)(ws + 0);            // 512
    float* colsumsq = (float*)(ws + 512);          // 512
    int* gh3        = (int*)(ws + 1024);           // 81380 -> 82404
    int* segK       = (int*)(ws + 82432);          // 81384 -> 163816
    int* cnt3       = (int*)(ws + 163840);         // 81380 -> 245220
    int* ssd        = (int*)(ws + 245248);         // 2560000 -> 2805248
    float* normd    = (float*)(ws + 2805248);      // 2560000 -> 5365248
    unsigned short* Wt      = (unsigned short*)(ws + 5365248);   // 2129920 -> 7495168
    unsigned short* Wrest   = (unsigned short*)(ws + 7495168);   // 32768   -> 7527936
    unsigned short* node_bf = (unsigned short*)(ws + 7527936);   // 5120000 -> 12647936
    float* resid    = (float*)(ws + 12647936);     // 10240000 -> 22887936
    float* hp0      = (float*)(ws + 22887936);     // 10240000 -> 33127936
    float* hp1      = (float*)(ws + 33127936);     // 10240000 -> 43367936
    float* W32      = (float*)(ws + 43367936);     // 4259840  -> 47627776
    float* h = (float*)d_out;

    hipMemsetAsync(ws, 0, 82432, stream);          // colsum, colsumsq, gh3
    k_prep1<<<3332, 256, 0, stream>>>(comp, basis, W32, etype, dst, gh3,
                                      node_feats, node_bf);
    k_prep2<<<344, 256, 0, stream>>>(gh3, segK, cnt3, W32, Wt, W_res, Wrest);
    k_scatter<<<2500, 256, 0, stream>>>(etype, src, dst, norm, cnt3, ssd, normd);
    k_fused<<<NB_CONV + NB_RES, 256, 0, stream>>>(segK, ssd, normd, node_bf,
                                                  Wt, Wrest, b_res, hp0, hp1, resid);
    k_combine<<<1250, 256, 0, stream>>>(hp0, hp1, resid, h_bias, h, colsum, colsumsq);
    k_bn<<<2500, 256, 0, stream>>>(h, colsum, colsumsq, gamma, beta);
}

// Round 4
// 344.630 us; speedup vs baseline: 2.5321x; 2.5321x over previous
//
#include <hip/hip_runtime.h>
#include <hip/hip_bf16.h>

// RGCN layer, MI355X — round 15: REVERT to r11 structure (proven 325us).
// r13/r14 post-mortem: fused LDS-accumulation is latency-dead — same ~6us
// tile-iteration cost as r11 but 40,690 half-empty tiles (vs 10,553 full)
// chained 33-deep in ~2 resident blocks/CU -> 588-660us, all pipes <5%.
// This round, two targeted fixes on r11:
// (1) conv epilogue: stage output tile in LDS (reuse Alds), store full 256B
//     rows (16 lanes x 16B) instead of 64B partial lines -> lift the 2.26TB/s
//     scattered-write ceiling.
// (2) reduce: single predicated 8-deep batch loop (was: serial dependent
//     4-row tail, ~half of dsts all-tail) + 2500 blocks (2 dsts/wave).

#define N_NODES 20000
#define E_EDGES 640000
#define R_REL   65
#define TM      64
#define NB_RESID 313
#define MAX_TILES 10240
#define SCAT_CH 2560

typedef __attribute__((ext_vector_type(8))) short bf16x8;
typedef __attribute__((ext_vector_type(4))) float f32x4;
typedef __attribute__((ext_vector_type(4))) unsigned int u32x4;
typedef __attribute__((ext_vector_type(2))) unsigned int u32x2;

__device__ __forceinline__ unsigned short f2bf(float x) {
    union { float f; unsigned int u; } c; c.f = x;
    unsigned int b = c.u + 0x7fffu + ((c.u >> 16) & 1u);   // RTNE
    return (unsigned short)(b >> 16);
}
__device__ __forceinline__ float bf2f_lo(unsigned int u) {
    union { unsigned int u; float f; } c; c.u = u << 16; return c.f;
}
__device__ __forceinline__ float bf2f_hi(unsigned int u) {
    union { unsigned int u; float f; } c; c.u = u & 0xffff0000u; return c.f;
}
__device__ __forceinline__ void async16(const void* g, void* l) {
    __builtin_amdgcn_global_load_lds(
        (const __attribute__((address_space(1))) unsigned int*)g,
        (__attribute__((address_space(3))) unsigned int*)l, 16, 0, 0);
}
__device__ __forceinline__ int unperm(int p) {      // permuted pos -> true col
    return (p & 64) + ((p & 3) << 4) + ((p >> 2) & 15);
}

// ---------------- K1: basis GEMM || etype+dst hist || f32->bf16 cvt --------
__global__ void k_prep1(const float* __restrict__ comp, const float* __restrict__ basis,
                        float* __restrict__ W32, const int* __restrict__ et,
                        const int* __restrict__ dstA, int* __restrict__ ghist,
                        int* __restrict__ gh2, const float* __restrict__ node_feats,
                        unsigned short* __restrict__ node_bf) {
    __shared__ float lc[16 * 65];
    __shared__ int lh[R_REL];
    int b = blockIdx.x, t = threadIdx.x;
    if (b < 320) {                                  // basis GEMM
        int r0 = (b >> 6) * 16;
        int col = (b & 63) * 256 + t;
        for (int j = t; j < 16 * 65; j += 256) {
            int rr = r0 + j / 65;
            lc[j] = (rr < R_REL) ? comp[rr * 65 + (j % 65)] : 0.f;
        }
        __syncthreads();
        float acc[16];
#pragma unroll
        for (int j = 0; j < 16; ++j) acc[j] = 0.f;
        for (int k = 0; k < 65; ++k) {
            float v = basis[k * 16384 + col];
#pragma unroll
            for (int j = 0; j < 16; ++j) acc[j] += lc[j * 65 + k] * v;
        }
#pragma unroll
        for (int j = 0; j < 16; ++j) {
            int rr = r0 + j;
            if (rr < R_REL) W32[rr * 16384 + col] = acc[j];
        }
    } else if (b < 832) {                           // histograms
        if (t < R_REL) lh[t] = 0;
        __syncthreads();
        for (int i = (b - 320) * 256 + t; i < E_EDGES; i += 512 * 256) {
            atomicAdd(&lh[et[i]], 1);
            atomicAdd(&gh2[dstA[i]], 1);
        }
        __syncthreads();
        if (t < R_REL) atomicAdd(&ghist[t], lh[t]);
    } else {                                        // cvt fp32 -> bf16 (x4)
        int i = (b - 832) * 256 + t;
        if (i < N_NODES * 32) {
            float4 v = reinterpret_cast<const float4*>(node_feats)[i];
            __hip_bfloat162 b0 = __float22bfloat162_rn(make_float2(v.x, v.y));
            __hip_bfloat162 b1 = __float22bfloat162_rn(make_float2(v.z, v.w));
            u32x2 pk;
            pk.x = *reinterpret_cast<unsigned int*>(&b0);
            pk.y = *reinterpret_cast<unsigned int*>(&b1);
            reinterpret_cast<u32x2*>(node_bf)[i] = pk;
        }
    }
}

// ---------------- K2: scanC (self prefix) || tiles || transposes -----------
__global__ void k_prep3(const int* __restrict__ gh2, int* __restrict__ cnt2,
                        int* __restrict__ seg, const int* __restrict__ ghist,
                        int* __restrict__ cnt, int* __restrict__ ntiles_p,
                        int* __restrict__ tile_rel, int* __restrict__ tile_start,
                        int* __restrict__ tile_len, const float* __restrict__ W32,
                        unsigned short* __restrict__ Wt, const float* __restrict__ Wresf,
                        unsigned short* __restrict__ Wrest) {
    int b = blockIdx.x, t = threadIdx.x;
    if (b < 80) {                                   // scanC with self-prefix
        __shared__ int red[256];
        __shared__ int pref;
        int acc = 0;
        for (int i = t; i < b * 256; i += 256) acc += gh2[i];
        red[t] = acc;
        __syncthreads();
        for (int off = 128; off > 0; off >>= 1) {
            if (t < off) red[t] += red[t + off];
            __syncthreads();
        }
        if (t == 0) pref = red[0];
        __syncthreads();
        int i = b * 256 + t;
        int v = (i < N_NODES) ? gh2[i] : 0;
        red[t] = v;
        __syncthreads();
        for (int off = 1; off < 256; off <<= 1) {
            int x = (t >= off) ? red[t - off] : 0;
            __syncthreads();
            red[t] += x;
            __syncthreads();
        }
        int excl = red[t] - v + pref;
        if (i < N_NODES) {
            cnt2[i] = excl;
            seg[i] = excl;
            if (i == N_NODES - 1) seg[N_NODES] = excl + v;
        }
    } else if (b == 80) {                           // ghist scan + tile descs
        __shared__ int base[R_REL + 1], tbase[R_REL + 1];
        int lane = t & 63;
        if (t < 64) {
            int v = ghist[lane];
            int x = v;
#pragma unroll
            for (int off = 1; off < 64; off <<= 1) {
                int y = __shfl_up(x, off);
                if (lane >= off) x += y;
            }
            base[lane] = x - v;
            if (lane == 63) {
                base[64] = x;
                base[65] = x + ghist[64];
            }
        }
        __syncthreads();
        if (t == 0) {
            int tb = 0;
            for (int r = 0; r < R_REL; ++r) {
                tbase[r] = tb;
                tb += (base[r + 1] - base[r] + TM - 1) / TM;
            }
            *ntiles_p = tb;
        }
        __syncthreads();
        if (t < R_REL) {
            cnt[t] = base[t];
            int s = base[t], e = base[t + 1], j = tbase[t];
            while (s < e) {
                int len = min(TM, e - s);
                tile_rel[j] = t; tile_start[j] = s; tile_len[j] = len;
                ++j; s += len;
            }
        }
    } else {                                        // transposes (264 blocks)
        __shared__ float tile[64][65];
        int bb = b - 81;
        const float* s; unsigned short* d; int sub;
        if (bb < R_REL * 4) { s = W32 + (size_t)(bb >> 2) * 16384; d = Wt + (size_t)(bb >> 2) * 16384; sub = bb & 3; }
        else { s = Wresf; d = Wrest; sub = bb - R_REL * 4; }
        int ot = (sub >> 1) & 1, itl = sub & 1;
        int tx = t & 63, ty = t >> 6;
        for (int it = 0; it < 16; ++it) {
            int i = ty + it * 4;
            tile[i][tx] = s[(itl * 64 + i) * 128 + ot * 64 + tx];
        }
        __syncthreads();
        for (int it = 0; it < 16; ++it) {
            int o = ty + it * 4;
            d[(ot * 64 + o) * 128 + itl * 64 + tx] = f2bf(tile[tx][o]);
        }
    }
}

// ---------------- K3: rel scatter + dst-position assignment ----------------
__global__ void k_scatter2(const int* __restrict__ et, const int* __restrict__ srcA,
                           const int* __restrict__ dstA, const float* __restrict__ norm,
                           int* __restrict__ cnt, int* __restrict__ cnt2,
                           int* __restrict__ srcp, float* __restrict__ normp,
                           int* __restrict__ inv2) {
    __shared__ int lh[R_REL], lbase[R_REL];
    int c0 = blockIdx.x * SCAT_CH;
    int cend = min(c0 + SCAT_CH, E_EDGES);
    if (threadIdx.x < R_REL) lh[threadIdx.x] = 0;
    __syncthreads();
    for (int i = c0 + threadIdx.x; i < cend; i += 256) atomicAdd(&lh[et[i]], 1);
    __syncthreads();
    if (threadIdx.x < R_REL && lh[threadIdx.x] > 0)
        lbase[threadIdx.x] = atomicAdd(&cnt[threadIdx.x], lh[threadIdx.x]);
    __syncthreads();
    if (threadIdx.x < R_REL) lh[threadIdx.x] = 0;
    __syncthreads();
    for (int i = c0 + threadIdx.x; i < cend; i += 256) {
        int r = et[i];
        int p = lbase[r] + atomicAdd(&lh[r], 1);
        srcp[p] = srcA[i];
        normp[p] = norm[i];
        inv2[p] = atomicAdd(&cnt2[dstA[i]], 1);
    }
}

// ---------------- K4: resid tiles + edge GEMM tiles (r9 structure) ---------
__global__ __launch_bounds__(256, 3) void k_conv_gemm(
    const int* __restrict__ tile_rel, const int* __restrict__ tile_start,
    const int* __restrict__ tile_len, const int* __restrict__ ntiles_p,
    const int* __restrict__ srcp, const float* __restrict__ normp,
    const unsigned short* __restrict__ node_bf,
    const unsigned short* __restrict__ Wt, const unsigned short* __restrict__ Wrest,
    const float* __restrict__ b_res, const int* __restrict__ inv2,
    unsigned short* __restrict__ t_out, float* __restrict__ resid) {
    __shared__ unsigned short Alds[64 * 128];
    __shared__ unsigned short Blds[128 * 128];
    __shared__ float snorm[64];
    __shared__ int sp2[64];
    int t = threadIdx.x;
    int w = t >> 6, lane = t & 63;
    int wr = (w >> 1) * 32, wc = (w & 1) * 64;
    int lrow = lane & 15, quad = lane >> 4;

    if (blockIdx.x < NB_RESID) {
        // ---- residual tile: rows row0..row0+63, relu(x@W_res+b) -> resid
        int row0 = blockIdx.x * 64;
        int nrows = min(64, N_NODES - row0);
#pragma unroll
        for (int it = 0; it < 8; ++it) {
            int j = t + 256 * it;
            int o = j >> 4, c = j & 15, cs = c ^ (o & 15);
            async16(Wrest + o * 128 + cs * 8, &Blds[o * 128 + c * 8]);
        }
#pragma unroll
        for (int it = 0; it < 4; ++it) {
            int j = t + 256 * it;
            int p = j >> 4, c = j & 15, cs = c ^ (p & 15);
            if (p < nrows)
                async16(node_bf + (size_t)(row0 + p) * 128 + cs * 8,
                        &Alds[p * 128 + c * 8]);
        }
        __syncthreads();
        f32x4 acc[2][4];
#pragma unroll
        for (int i = 0; i < 2; ++i)
#pragma unroll
            for (int j = 0; j < 4; ++j) acc[i][j] = (f32x4){0.f, 0.f, 0.f, 0.f};
#pragma unroll
        for (int ks = 0; ks < 4; ++ks) {
            int cs = (ks * 4 + quad) ^ lrow;
            bf16x8 af[2], bfr[4];
#pragma unroll
            for (int i = 0; i < 2; ++i)
                af[i] = *reinterpret_cast<const bf16x8*>(&Alds[(wr + i * 16 + lrow) * 128 + cs * 8]);
#pragma unroll
            for (int j = 0; j < 4; ++j)
                bfr[j] = *reinterpret_cast<const bf16x8*>(&Blds[(wc + j * 16 + lrow) * 128 + cs * 8]);
#pragma unroll
            for (int i = 0; i < 2; ++i)
#pragma unroll
                for (int j = 0; j < 4; ++j)
                    acc[i][j] = __builtin_amdgcn_mfma_f32_16x16x32_bf16(af[i], bfr[j], acc[i][j], 0, 0, 0);
        }
        float br0 = b_res[wc + lrow];
        float br1 = b_res[wc + 16 + lrow];
        float br2 = b_res[wc + 32 + lrow];
        float br3 = b_res[wc + 48 + lrow];
#pragma unroll
        for (int i = 0; i < 2; ++i) {
#pragma unroll
            for (int reg = 0; reg < 4; ++reg) {
                int grow = row0 + wr + i * 16 + quad * 4 + reg;
                if (grow < N_NODES) {
                    float4 v;
                    v.x = fmaxf(acc[i][0][reg] + br0, 0.f);
                    v.y = fmaxf(acc[i][1][reg] + br1, 0.f);
                    v.z = fmaxf(acc[i][2][reg] + br2, 0.f);
                    v.w = fmaxf(acc[i][3][reg] + br3, 0.f);
                    *reinterpret_cast<float4*>(resid + (size_t)grow * 128 + wc + lrow * 4) = v;
                }
            }
        }
        return;
    }

    // ---- edge tile (r5/r9 structure)
    int tid = blockIdx.x - NB_RESID;
    if (tid >= *ntiles_p) return;
    int r = tile_rel[tid], start = tile_start[tid], len = tile_len[tid];
    const unsigned short* Wr = Wt + (size_t)r * 16384;
#pragma unroll
    for (int it = 0; it < 8; ++it) {               // stage W (XOR on source)
        int j = t + 256 * it;
        int o = j >> 4, c = j & 15, cs = c ^ (o & 15);
        async16(Wr + o * 128 + cs * 8, &Blds[o * 128 + c * 8]);
    }
#pragma unroll
    for (int it = 0; it < 4; ++it) {               // stage A (gathered rows)
        int j = t + 256 * it;
        int p = j >> 4, c = j & 15, cs = c ^ (p & 15);
        if (p < len)
            async16(node_bf + (size_t)srcp[start + p] * 128 + cs * 8,
                    &Alds[p * 128 + c * 8]);
    }
    if (t < TM && t < len) {
        snorm[t] = normp[start + t];
        sp2[t] = inv2[start + t];
    }
    __syncthreads();

    f32x4 acc[2][4];
#pragma unroll
    for (int i = 0; i < 2; ++i)
#pragma unroll
        for (int j = 0; j < 4; ++j) acc[i][j] = (f32x4){0.f, 0.f, 0.f, 0.f};
#pragma unroll
    for (int ks = 0; ks < 4; ++ks) {
        int cs = (ks * 4 + quad) ^ lrow;
        bf16x8 af[2], bfr[4];
#pragma unroll
        for (int i = 0; i < 2; ++i)
            af[i] = *reinterpret_cast<const bf16x8*>(&Alds[(wr + i * 16 + lrow) * 128 + cs * 8]);
#pragma unroll
        for (int j = 0; j < 4; ++j)
            bfr[j] = *reinterpret_cast<const bf16x8*>(&Blds[(wc + j * 16 + lrow) * 128 + cs * 8]);
#pragma unroll
        for (int i = 0; i < 2; ++i)
#pragma unroll
            for (int j = 0; j < 4; ++j)
                acc[i][j] = __builtin_amdgcn_mfma_f32_16x16x32_bf16(af[i], bfr[j], acc[i][j], 0, 0, 0);
    }

    // epilogue: scale by norm, pack bf16, stage tile in LDS (reuse Alds),
    // then full 256B-row coalesced stores (16 lanes x 16B per row).
    // r11 wrote 64B partial lines per wave at scattered p2 rows (2.26 TB/s);
    // full-line scattered writes should lift the write-side BW.
    __syncthreads();                                // all MFMA reads of Alds done
#pragma unroll
    for (int i = 0; i < 2; ++i) {
        int m0 = wr + i * 16 + quad * 4;
#pragma unroll
        for (int reg = 0; reg < 4; ++reg) {
            int m = m0 + reg;
            if (m < len) {
                float nm = snorm[m];
                float2 lo2 = make_float2(acc[i][0][reg] * nm, acc[i][1][reg] * nm);
                float2 hi2 = make_float2(acc[i][2][reg] * nm, acc[i][3][reg] * nm);
                __hip_bfloat162 blo = __float22bfloat162_rn(lo2);
                __hip_bfloat162 bhi = __float22bfloat162_rn(hi2);
                u32x2 st;
                st.x = *reinterpret_cast<unsigned int*>(&blo);
                st.y = *reinterpret_cast<unsigned int*>(&bhi);
                *reinterpret_cast<u32x2*>(&Alds[m * 128 + wc + lrow * 4]) = st;
            }
        }
    }
    __syncthreads();
#pragma unroll
    for (int it2 = 0; it2 < 4; ++it2) {
        int row = it2 * 16 + (t >> 4);
        int sub = t & 15;
        if (row < len) {
            u32x4 v = *reinterpret_cast<const u32x4*>(&Alds[row * 128 + sub * 8]);
            *reinterpret_cast<u32x4*>(t_out + (size_t)sp2[row] * 128 + sub * 8) = v;
        }
    }
}

// ---------------- K5: wave-per-dst CSR reduce, predicated 8-batch ----------
__global__ __launch_bounds__(256) void k_reduce_fused(
    const unsigned short* __restrict__ t, const int* __restrict__ seg,
    const float* __restrict__ resid, const float* __restrict__ h_bias,
    float* __restrict__ h, float* __restrict__ colsum, float* __restrict__ colsumsq) {
    __shared__ float cs1[128], cs2[128], sbias[128];
    if (threadIdx.x < 128) {
        cs1[threadIdx.x] = 0.f; cs2[threadIdx.x] = 0.f;
        sbias[threadIdx.x] = h_bias[unperm(threadIdx.x)];
    }
    __syncthreads();
    int w = threadIdx.x >> 6, lane = threadIdx.x & 63;
    int g = lane >> 4, c = lane & 15;
    for (int k = 0; k < 2; ++k) {
        int d = blockIdx.x * 8 + k * 4 + w;
        int a = seg[d], b = seg[d + 1];
        float s[8];
#pragma unroll
        for (int kk = 0; kk < 8; ++kk) s[kk] = 0.f;
        for (int q = a + g; q < b; q += 32) {
            u32x4 v[8];
#pragma unroll
            for (int kk = 0; kk < 8; ++kk) {
                int row = q + 4 * kk;
                int rc = (row < b) ? row : a;       // clamp -> loads all issue
                v[kk] = *reinterpret_cast<const u32x4*>(t + (size_t)rc * 128 + c * 8);
                if (row >= b) v[kk] = (u32x4){0u, 0u, 0u, 0u};
            }
#pragma unroll
            for (int kk = 0; kk < 8; ++kk)
#pragma unroll
                for (int j = 0; j < 4; ++j) {
                    s[2 * j]     += bf2f_lo(v[kk][j]);
                    s[2 * j + 1] += bf2f_hi(v[kk][j]);
                }
        }
#pragma unroll
        for (int kk = 0; kk < 8; ++kk) {
            s[kk] += __shfl_xor(s[kk], 16);
            s[kk] += __shfl_xor(s[kk], 32);
        }
        if (g == 0) {
            const float* rp = resid + (size_t)d * 128 + c * 8;
            float4 r0 = *reinterpret_cast<const float4*>(rp);
            float4 r1 = *reinterpret_cast<const float4*>(rp + 4);
            float rr[8] = {r0.x, r0.y, r0.z, r0.w, r1.x, r1.y, r1.z, r1.w};
            float v[8];
#pragma unroll
            for (int kk = 0; kk < 8; ++kk)
                v[kk] = fmaxf(s[kk] + sbias[c * 8 + kk], 0.f) + rr[kk];
            float* hp = h + (size_t)d * 128 + c * 8;
            *reinterpret_cast<float4*>(hp)     = make_float4(v[0], v[1], v[2], v[3]);
            *reinterpret_cast<float4*>(hp + 4) = make_float4(v[4], v[5], v[6], v[7]);
#pragma unroll
            for (int kk = 0; kk < 8; ++kk) {
                atomicAdd(&cs1[c * 8 + kk], v[kk]);
                atomicAdd(&cs2[c * 8 + kk], v[kk] * v[kk]);
            }
        }
    }
    __syncthreads();
    if (threadIdx.x < 128) {
        atomicAdd(&colsum[threadIdx.x], cs1[threadIdx.x]);
        atomicAdd(&colsumsq[threadIdx.x], cs2[threadIdx.x]);
    }
}

// ---------------- K6: BN apply + unpermute to natural cols -----------------
__global__ void k_bn(float* __restrict__ h, const float* __restrict__ colsum,
                     const float* __restrict__ colsumsq, const float* __restrict__ gamma,
                     const float* __restrict__ beta) {
    __shared__ float sc[128], sh[128], tile[8][128];
    int t = threadIdx.x;
    if (t < 128) {
        int n = unperm(t);
        float m = colsum[t] * (1.f / N_NODES);
        float var = colsumsq[t] * (1.f / N_NODES) - m * m;
        float s = gamma[n] * rsqrtf(var + 1e-5f);
        sc[t] = s;
        sh[t] = beta[n] - m * s;
    }
    __syncthreads();
    int r = t >> 5;
    int p0 = (t & 31) * 4;
    int n0 = (p0 & 64) + ((p0 >> 2) & 15);
    for (int row0 = blockIdx.x * 8; row0 < N_NODES; row0 += gridDim.x * 8) {
        int row = row0 + r;
        float4 v = make_float4(0.f, 0.f, 0.f, 0.f);
        if (row < N_NODES) v = *reinterpret_cast<float4*>(h + (size_t)row * 128 + p0);
        v.x = v.x * sc[p0] + sh[p0];
        v.y = v.y * sc[p0 + 1] + sh[p0 + 1];
        v.z = v.z * sc[p0 + 2] + sh[p0 + 2];
        v.w = v.w * sc[p0 + 3] + sh[p0 + 3];
        tile[r][n0]      = v.x;
        tile[r][n0 + 16] = v.y;
        tile[r][n0 + 32] = v.z;
        tile[r][n0 + 48] = v.w;
        __syncthreads();
        if (row < N_NODES)
            *reinterpret_cast<float4*>(h + (size_t)row * 128 + p0) =
                *reinterpret_cast<float4*>(&tile[r][p0]);
        __syncthreads();
    }
}

extern "C" void kernel_launch(void* const* d_in, const int* in_sizes, int n_in,
                              void* d_out, int out_size, void* d_ws, size_t ws_size,
                              hipStream_t stream) {
    (void)in_sizes; (void)n_in; (void)out_size; (void)ws_size;
    const float* node_feats = (const float*)d_in[0];
    const int* src    = (const int*)d_in[1];
    const int* dst    = (const int*)d_in[2];
    const int* etype  = (const int*)d_in[3];
    const float* norm = (const float*)d_in[4];
    const float* basis = (const float*)d_in[5];
    const float* comp  = (const float*)d_in[6];
    const float* h_bias = (const float*)d_in[7];
    const float* W_res  = (const float*)d_in[8];
    const float* b_res  = (const float*)d_in[9];
    const float* gamma  = (const float*)d_in[10];
    const float* beta   = (const float*)d_in[11];

    char* ws = (char*)d_ws;
    int* ghist      = (int*)(ws + 0);
    int* cnt        = (int*)(ws + 1024);
    int* ntiles_p   = (int*)(ws + 2048);
    float* colsum   = (float*)(ws + 2560);
    float* colsumsq = (float*)(ws + 3072);
    int* gh2        = (int*)(ws + 8192);       // 80000 -> 88192
    int* tile_rel   = (int*)(ws + 88192);      // 40960
    int* tile_start = (int*)(ws + 129152);     // 40960
    int* tile_len   = (int*)(ws + 170112);     // 40960 -> 211072
    unsigned short* Wt      = (unsigned short*)(ws + 211072);    // 2129920 -> 2340992
    unsigned short* Wrest   = (unsigned short*)(ws + 2340992);   // 32768   -> 2373760
    unsigned short* node_bf = (unsigned short*)(ws + 2373760);   // 5120000 -> 7493760
    int* srcp       = (int*)(ws + 7493760);    // 2560000 -> 10053760
    float* normp    = (float*)(ws + 10053760); // 2560000 -> 12613760
    int* inv2       = (int*)(ws + 12613760);   // 2560000 -> 15173760
    float* resid    = (float*)(ws + 15173760); // 10240000 -> 25413760
    int* seg        = (int*)(ws + 25413760);   // 80004 -> 25493764, pad
    int* cnt2       = (int*)(ws + 25493776);   // 80000 -> 25573776
    const long T_BASE = 25573776L;             // 16B aligned
    float* W32      = (float*)(ws + T_BASE);   // aliased: dead before conv
    unsigned short* t_buf = (unsigned short*)(ws + T_BASE);      // 163.84 MB
    float* hacc = (float*)d_out;

    hipMemsetAsync(ws, 0, 88192, stream);
    k_prep1<<<3332, 256, 0, stream>>>(comp, basis, W32, etype, dst, ghist, gh2,
                                      node_feats, node_bf);
    k_prep3<<<345, 256, 0, stream>>>(gh2, cnt2, seg, ghist, cnt, ntiles_p,
                                     tile_rel, tile_start, tile_len,
                                     W32, Wt, W_res, Wrest);
    k_scatter2<<<(E_EDGES + SCAT_CH - 1) / SCAT_CH, 256, 0, stream>>>(
        etype, src, dst, norm, cnt, cnt2, srcp, normp, inv2);
    k_conv_gemm<<<NB_RESID + MAX_TILES, 256, 0, stream>>>(
        tile_rel, tile_start, tile_len, ntiles_p, srcp, normp, node_bf,
        Wt, Wrest, b_res, inv2, t_buf, resid);
    k_reduce_fused<<<N_NODES / 8, 256, 0, stream>>>(t_buf, seg, resid, h_bias,
                                                    hacc, colsum, colsumsq);
    k_bn<<<2500, 256, 0, stream>>>(hacc, colsum, colsumsq, gamma, beta);
}

// Round 5
// 344.505 us; speedup vs baseline: 2.5330x; 1.0004x over previous
//
#include <hip/hip_runtime.h>
#include <hip/hip_bf16.h>

// RGCN layer, MI355X — round 16.
// r15 post-mortem: full-line staged epilogue was neutral (87.8 vs 84.2) —
// partial lines were never the issue; the t_buf write SCATTER (dst-order
// positions across 164MB) is. FIX: write t_buf SEQUENTIALLY (rel-order,
// t_buf[start+m]), move the permutation to reduce via eidx[] (built in
// scatter2 with the same atomic it already did). Reduce gathers
// t_buf[eidx[q]] — scattered 256B READS from the LLC-resident buffer.
// Also: 128-row edge tiles (10240 -> ~5065 tiles) halve W staging traffic
// and barriers; LDS 66KB -> 2 blocks/CU; conv epilogue = direct sequential
// full-line stores, inv2/sp2 dropped from conv.

#define N_NODES 20000
#define E_EDGES 640000
#define R_REL   65
#define TM      128
#define NB_RESID 313
#define MAX_TILES 5120
#define SCAT_CH 2560

typedef __attribute__((ext_vector_type(8))) short bf16x8;
typedef __attribute__((ext_vector_type(4))) float f32x4;
typedef __attribute__((ext_vector_type(4))) unsigned int u32x4;
typedef __attribute__((ext_vector_type(2))) unsigned int u32x2;

__device__ __forceinline__ unsigned short f2bf(float x) {
    union { float f; unsigned int u; } c; c.f = x;
    unsigned int b = c.u + 0x7fffu + ((c.u >> 16) & 1u);   // RTNE
    return (unsigned short)(b >> 16);
}
__device__ __forceinline__ float bf2f_lo(unsigned int u) {
    union { unsigned int u; float f; } c; c.u = u << 16; return c.f;
}
__device__ __forceinline__ float bf2f_hi(unsigned int u) {
    union { unsigned int u; float f; } c; c.u = u & 0xffff0000u; return c.f;
}
__device__ __forceinline__ void async16(const void* g, void* l) {
    __builtin_amdgcn_global_load_lds(
        (const __attribute__((address_space(1))) unsigned int*)g,
        (__attribute__((address_space(3))) unsigned int*)l, 16, 0, 0);
}
__device__ __forceinline__ int unperm(int p) {      // permuted pos -> true col
    return (p & 64) + ((p & 3) << 4) + ((p >> 2) & 15);
}

// ---------------- K1: basis GEMM || etype+dst hist || f32->bf16 cvt --------
__global__ void k_prep1(const float* __restrict__ comp, const float* __restrict__ basis,
                        float* __restrict__ W32, const int* __restrict__ et,
                        const int* __restrict__ dstA, int* __restrict__ ghist,
                        int* __restrict__ gh2, const float* __restrict__ node_feats,
                        unsigned short* __restrict__ node_bf) {
    __shared__ float lc[16 * 65];
    __shared__ int lh[R_REL];
    int b = blockIdx.x, t = threadIdx.x;
    if (b < 320) {                                  // basis GEMM
        int r0 = (b >> 6) * 16;
        int col = (b & 63) * 256 + t;
        for (int j = t; j < 16 * 65; j += 256) {
            int rr = r0 + j / 65;
            lc[j] = (rr < R_REL) ? comp[rr * 65 + (j % 65)] : 0.f;
        }
        __syncthreads();
        float acc[16];
#pragma unroll
        for (int j = 0; j < 16; ++j) acc[j] = 0.f;
        for (int k = 0; k < 65; ++k) {
            float v = basis[k * 16384 + col];
#pragma unroll
            for (int j = 0; j < 16; ++j) acc[j] += lc[j * 65 + k] * v;
        }
#pragma unroll
        for (int j = 0; j < 16; ++j) {
            int rr = r0 + j;
            if (rr < R_REL) W32[rr * 16384 + col] = acc[j];
        }
    } else if (b < 832) {                           // histograms
        if (t < R_REL) lh[t] = 0;
        __syncthreads();
        for (int i = (b - 320) * 256 + t; i < E_EDGES; i += 512 * 256) {
            atomicAdd(&lh[et[i]], 1);
            atomicAdd(&gh2[dstA[i]], 1);
        }
        __syncthreads();
        if (t < R_REL) atomicAdd(&ghist[t], lh[t]);
    } else {                                        // cvt fp32 -> bf16 (x4)
        int i = (b - 832) * 256 + t;
        if (i < N_NODES * 32) {
            float4 v = reinterpret_cast<const float4*>(node_feats)[i];
            __hip_bfloat162 b0 = __float22bfloat162_rn(make_float2(v.x, v.y));
            __hip_bfloat162 b1 = __float22bfloat162_rn(make_float2(v.z, v.w));
            u32x2 pk;
            pk.x = *reinterpret_cast<unsigned int*>(&b0);
            pk.y = *reinterpret_cast<unsigned int*>(&b1);
            reinterpret_cast<u32x2*>(node_bf)[i] = pk;
        }
    }
}

// ---------------- K2: scanC (self prefix) || tiles || transposes -----------
__global__ void k_prep3(const int* __restrict__ gh2, int* __restrict__ cnt2,
                        int* __restrict__ seg, const int* __restrict__ ghist,
                        int* __restrict__ cnt, int* __restrict__ ntiles_p,
                        int* __restrict__ tile_rel, int* __restrict__ tile_start,
                        int* __restrict__ tile_len, const float* __restrict__ W32,
                        unsigned short* __restrict__ Wt, const float* __restrict__ Wresf,
                        unsigned short* __restrict__ Wrest) {
    int b = blockIdx.x, t = threadIdx.x;
    if (b < 80) {                                   // scanC with self-prefix
        __shared__ int red[256];
        __shared__ int pref;
        int acc = 0;
        for (int i = t; i < b * 256; i += 256) acc += gh2[i];
        red[t] = acc;
        __syncthreads();
        for (int off = 128; off > 0; off >>= 1) {
            if (t < off) red[t] += red[t + off];
            __syncthreads();
        }
        if (t == 0) pref = red[0];
        __syncthreads();
        int i = b * 256 + t;
        int v = (i < N_NODES) ? gh2[i] : 0;
        red[t] = v;
        __syncthreads();
        for (int off = 1; off < 256; off <<= 1) {
            int x = (t >= off) ? red[t - off] : 0;
            __syncthreads();
            red[t] += x;
            __syncthreads();
        }
        int excl = red[t] - v + pref;
        if (i < N_NODES) {
            cnt2[i] = excl;
            seg[i] = excl;
            if (i == N_NODES - 1) seg[N_NODES] = excl + v;
        }
    } else if (b == 80) {                           // ghist scan + tile descs
        __shared__ int base[R_REL + 1], tbase[R_REL + 1];
        int lane = t & 63;
        if (t < 64) {
            int v = ghist[lane];
            int x = v;
#pragma unroll
            for (int off = 1; off < 64; off <<= 1) {
                int y = __shfl_up(x, off);
                if (lane >= off) x += y;
            }
            base[lane] = x - v;
            if (lane == 63) {
                base[64] = x;
                base[65] = x + ghist[64];
            }
        }
        __syncthreads();
        if (t == 0) {
            int tb = 0;
            for (int r = 0; r < R_REL; ++r) {
                tbase[r] = tb;
                tb += (base[r + 1] - base[r] + TM - 1) / TM;
            }
            *ntiles_p = tb;
        }
        __syncthreads();
        if (t < R_REL) {
            cnt[t] = base[t];
            int s = base[t], e = base[t + 1], j = tbase[t];
            while (s < e) {
                int len = min(TM, e - s);
                tile_rel[j] = t; tile_start[j] = s; tile_len[j] = len;
                ++j; s += len;
            }
        }
    } else {                                        // transposes (264 blocks)
        __shared__ float tile[64][65];
        int bb = b - 81;
        const float* s; unsigned short* d; int sub;
        if (bb < R_REL * 4) { s = W32 + (size_t)(bb >> 2) * 16384; d = Wt + (size_t)(bb >> 2) * 16384; sub = bb & 3; }
        else { s = Wresf; d = Wrest; sub = bb - R_REL * 4; }
        int ot = (sub >> 1) & 1, itl = sub & 1;
        int tx = t & 63, ty = t >> 6;
        for (int it = 0; it < 16; ++it) {
            int i = ty + it * 4;
            tile[i][tx] = s[(itl * 64 + i) * 128 + ot * 64 + tx];
        }
        __syncthreads();
        for (int it = 0; it < 16; ++it) {
            int o = ty + it * 4;
            d[(ot * 64 + o) * 128 + itl * 64 + tx] = f2bf(tile[tx][o]);
        }
    }
}

// ---------------- K3: rel scatter + dst-order index build ------------------
__global__ void k_scatter2(const int* __restrict__ et, const int* __restrict__ srcA,
                           const int* __restrict__ dstA, const float* __restrict__ norm,
                           int* __restrict__ cnt, int* __restrict__ cnt2,
                           int* __restrict__ srcp, float* __restrict__ normp,
                           int* __restrict__ eidx) {
    __shared__ int lh[R_REL], lbase[R_REL];
    int c0 = blockIdx.x * SCAT_CH;
    int cend = min(c0 + SCAT_CH, E_EDGES);
    if (threadIdx.x < R_REL) lh[threadIdx.x] = 0;
    __syncthreads();
    for (int i = c0 + threadIdx.x; i < cend; i += 256) atomicAdd(&lh[et[i]], 1);
    __syncthreads();
    if (threadIdx.x < R_REL && lh[threadIdx.x] > 0)
        lbase[threadIdx.x] = atomicAdd(&cnt[threadIdx.x], lh[threadIdx.x]);
    __syncthreads();
    if (threadIdx.x < R_REL) lh[threadIdx.x] = 0;
    __syncthreads();
    for (int i = c0 + threadIdx.x; i < cend; i += 256) {
        int r = et[i];
        int p = lbase[r] + atomicAdd(&lh[r], 1);    // rel-order position
        srcp[p] = srcA[i];
        normp[p] = norm[i];
        int pos = atomicAdd(&cnt2[dstA[i]], 1);     // dst-order position
        eidx[pos] = p;                              // dst-order -> rel-order map
    }
}

// ---------------- K4: resid tiles + 128-row edge GEMM tiles ----------------
__global__ __launch_bounds__(256, 2) void k_conv_gemm(
    const int* __restrict__ tile_rel, const int* __restrict__ tile_start,
    const int* __restrict__ tile_len, const int* __restrict__ ntiles_p,
    const int* __restrict__ srcp, const float* __restrict__ normp,
    const unsigned short* __restrict__ node_bf,
    const unsigned short* __restrict__ Wt, const unsigned short* __restrict__ Wrest,
    const float* __restrict__ b_res, unsigned short* __restrict__ t_out,
    float* __restrict__ resid) {
    __shared__ unsigned short Alds[128 * 128];      // 32 KB
    __shared__ unsigned short Blds[128 * 128];      // 32 KB
    __shared__ float snorm[128];
    int t = threadIdx.x;
    int w = t >> 6, lane = t & 63;
    int lrow = lane & 15, quad = lane >> 4;

    if (blockIdx.x < NB_RESID) {
        // ---- residual tile: rows row0..row0+63, relu(x@W_res+b) -> resid
        int wr = (w >> 1) * 32, wc = (w & 1) * 64;
        int row0 = blockIdx.x * 64;
        int nrows = min(64, N_NODES - row0);
#pragma unroll
        for (int it = 0; it < 8; ++it) {
            int j = t + 256 * it;
            int o = j >> 4, c = j & 15, cs = c ^ (o & 15);
            async16(Wrest + o * 128 + cs * 8, &Blds[o * 128 + c * 8]);
        }
#pragma unroll
        for (int it = 0; it < 4; ++it) {
            int j = t + 256 * it;
            int p = j >> 4, c = j & 15, cs = c ^ (p & 15);
            if (p < nrows)
                async16(node_bf + (size_t)(row0 + p) * 128 + cs * 8,
                        &Alds[p * 128 + c * 8]);
        }
        __syncthreads();
        f32x4 acc[2][4];
#pragma unroll
        for (int i = 0; i < 2; ++i)
#pragma unroll
            for (int j = 0; j < 4; ++j) acc[i][j] = (f32x4){0.f, 0.f, 0.f, 0.f};
#pragma unroll
        for (int ks = 0; ks < 4; ++ks) {
            int cs = (ks * 4 + quad) ^ lrow;
            bf16x8 af[2], bfr[4];
#pragma unroll
            for (int i = 0; i < 2; ++i)
                af[i] = *reinterpret_cast<const bf16x8*>(&Alds[(wr + i * 16 + lrow) * 128 + cs * 8]);
#pragma unroll
            for (int j = 0; j < 4; ++j)
                bfr[j] = *reinterpret_cast<const bf16x8*>(&Blds[(wc + j * 16 + lrow) * 128 + cs * 8]);
#pragma unroll
            for (int i = 0; i < 2; ++i)
#pragma unroll
                for (int j = 0; j < 4; ++j)
                    acc[i][j] = __builtin_amdgcn_mfma_f32_16x16x32_bf16(af[i], bfr[j], acc[i][j], 0, 0, 0);
        }
        float br0 = b_res[wc + lrow];
        float br1 = b_res[wc + 16 + lrow];
        float br2 = b_res[wc + 32 + lrow];
        float br3 = b_res[wc + 48 + lrow];
#pragma unroll
        for (int i = 0; i < 2; ++i) {
#pragma unroll
            for (int reg = 0; reg < 4; ++reg) {
                int grow = row0 + wr + i * 16 + quad * 4 + reg;
                if (grow < N_NODES) {
                    float4 v;
                    v.x = fmaxf(acc[i][0][reg] + br0, 0.f);
                    v.y = fmaxf(acc[i][1][reg] + br1, 0.f);
                    v.z = fmaxf(acc[i][2][reg] + br2, 0.f);
                    v.w = fmaxf(acc[i][3][reg] + br3, 0.f);
                    *reinterpret_cast<float4*>(resid + (size_t)grow * 128 + wc + lrow * 4) = v;
                }
            }
        }
        return;
    }

    // ---- edge tile: 128 rows x 128 cols, wave w owns rows w*32..+31
    int tid = blockIdx.x - NB_RESID;
    if (tid >= *ntiles_p) return;
    int r = tile_rel[tid], start = tile_start[tid], len = tile_len[tid];
    int wr = w * 32;
    const unsigned short* Wr = Wt + (size_t)r * 16384;
#pragma unroll
    for (int it = 0; it < 8; ++it) {               // stage W (XOR on source)
        int j = t + 256 * it;
        int o = j >> 4, c = j & 15, cs = c ^ (o & 15);
        async16(Wr + o * 128 + cs * 8, &Blds[o * 128 + c * 8]);
    }
#pragma unroll
    for (int it = 0; it < 8; ++it) {               // stage A (gathered rows)
        int j = t + 256 * it;
        int p = j >> 4, c = j & 15, cs = c ^ (p & 15);
        if (p < len)
            async16(node_bf + (size_t)srcp[start + p] * 128 + cs * 8,
                    &Alds[p * 128 + c * 8]);
    }
    if (t < TM && t < len) snorm[t] = normp[start + t];
    __syncthreads();

    f32x4 acc[2][8];
#pragma unroll
    for (int i = 0; i < 2; ++i)
#pragma unroll
        for (int j = 0; j < 8; ++j) acc[i][j] = (f32x4){0.f, 0.f, 0.f, 0.f};
#pragma unroll
    for (int ks = 0; ks < 4; ++ks) {
        int cs = (ks * 4 + quad) ^ lrow;
        bf16x8 af[2], bfr[8];
#pragma unroll
        for (int i = 0; i < 2; ++i)
            af[i] = *reinterpret_cast<const bf16x8*>(&Alds[(wr + i * 16 + lrow) * 128 + cs * 8]);
#pragma unroll
        for (int j = 0; j < 8; ++j)
            bfr[j] = *reinterpret_cast<const bf16x8*>(&Blds[(j * 16 + lrow) * 128 + cs * 8]);
#pragma unroll
        for (int i = 0; i < 2; ++i)
#pragma unroll
            for (int j = 0; j < 8; ++j)
                acc[i][j] = __builtin_amdgcn_mfma_f32_16x16x32_bf16(af[i], bfr[j], acc[i][j], 0, 0, 0);
    }

    // epilogue: scale by norm, pack bf16, direct SEQUENTIAL full-line stores.
    // stored col position p = 64*(j>>2) + lrow*4 + (j&3); unperm() recovers
    // true col = 64*(j>>2) + (j&3)*16 + lrow (same permutation as r11).
#pragma unroll
    for (int i = 0; i < 2; ++i) {
        int m0 = wr + i * 16 + quad * 4;
#pragma unroll
        for (int reg = 0; reg < 4; ++reg) {
            int m = m0 + reg;
            if (m < len) {
                float nm = snorm[m];
                float2 l0 = make_float2(acc[i][0][reg] * nm, acc[i][1][reg] * nm);
                float2 l1 = make_float2(acc[i][2][reg] * nm, acc[i][3][reg] * nm);
                float2 h0 = make_float2(acc[i][4][reg] * nm, acc[i][5][reg] * nm);
                float2 h1 = make_float2(acc[i][6][reg] * nm, acc[i][7][reg] * nm);
                __hip_bfloat162 bl0 = __float22bfloat162_rn(l0);
                __hip_bfloat162 bl1 = __float22bfloat162_rn(l1);
                __hip_bfloat162 bh0 = __float22bfloat162_rn(h0);
                __hip_bfloat162 bh1 = __float22bfloat162_rn(h1);
                u32x2 s0, s1;
                s0.x = *reinterpret_cast<unsigned int*>(&bl0);
                s0.y = *reinterpret_cast<unsigned int*>(&bl1);
                s1.x = *reinterpret_cast<unsigned int*>(&bh0);
                s1.y = *reinterpret_cast<unsigned int*>(&bh1);
                unsigned short* rowp = t_out + (size_t)(start + m) * 128;
                *reinterpret_cast<u32x2*>(rowp + lrow * 4)      = s0;
                *reinterpret_cast<u32x2*>(rowp + 64 + lrow * 4) = s1;
            }
        }
    }
}

// ---------------- K5: wave-per-dst reduce via eidx gather ------------------
__global__ __launch_bounds__(256) void k_reduce_fused(
    const unsigned short* __restrict__ t, const int* __restrict__ seg,
    const int* __restrict__ eidx, const float* __restrict__ resid,
    const float* __restrict__ h_bias, float* __restrict__ h,
    float* __restrict__ colsum, float* __restrict__ colsumsq) {
    __shared__ float cs1[128], cs2[128], sbias[128];
    if (threadIdx.x < 128) {
        cs1[threadIdx.x] = 0.f; cs2[threadIdx.x] = 0.f;
        sbias[threadIdx.x] = h_bias[unperm(threadIdx.x)];
    }
    __syncthreads();
    int w = threadIdx.x >> 6, lane = threadIdx.x & 63;
    int g = lane >> 4, c = lane & 15;
    for (int k = 0; k < 2; ++k) {
        int d = blockIdx.x * 8 + k * 4 + w;
        int a = seg[d], b = seg[d + 1];
        float s[8];
#pragma unroll
        for (int kk = 0; kk < 8; ++kk) s[kk] = 0.f;
        for (int q = a + g; q < b; q += 32) {
            int er[8];
#pragma unroll
            for (int kk = 0; kk < 8; ++kk) {
                int row = q + 4 * kk;
                er[kk] = eidx[(row < b) ? row : a];
            }
            u32x4 v[8];
#pragma unroll
            for (int kk = 0; kk < 8; ++kk) {
                v[kk] = *reinterpret_cast<const u32x4*>(t + (size_t)er[kk] * 128 + c * 8);
                if (q + 4 * kk >= b) v[kk] = (u32x4){0u, 0u, 0u, 0u};
            }
#pragma unroll
            for (int kk = 0; kk < 8; ++kk)
#pragma unroll
                for (int j = 0; j < 4; ++j) {
                    s[2 * j]     += bf2f_lo(v[kk][j]);
                    s[2 * j + 1] += bf2f_hi(v[kk][j]);
                }
        }
#pragma unroll
        for (int kk = 0; kk < 8; ++kk) {
            s[kk] += __shfl_xor(s[kk], 16);
            s[kk] += __shfl_xor(s[kk], 32);
        }
        if (g == 0) {
            const float* rp = resid + (size_t)d * 128 + c * 8;
            float4 r0 = *reinterpret_cast<const float4*>(rp);
            float4 r1 = *reinterpret_cast<const float4*>(rp + 4);
            float rr[8] = {r0.x, r0.y, r0.z, r0.w, r1.x, r1.y, r1.z, r1.w};
            float v[8];
#pragma unroll
            for (int kk = 0; kk < 8; ++kk)
                v[kk] = fmaxf(s[kk] + sbias[c * 8 + kk], 0.f) + rr[kk];
            float* hp = h + (size_t)d * 128 + c * 8;
            *reinterpret_cast<float4*>(hp)     = make_float4(v[0], v[1], v[2], v[3]);
            *reinterpret_cast<float4*>(hp + 4) = make_float4(v[4], v[5], v[6], v[7]);
#pragma unroll
            for (int kk = 0; kk < 8; ++kk) {
                atomicAdd(&cs1[c * 8 + kk], v[kk]);
                atomicAdd(&cs2[c * 8 + kk], v[kk] * v[kk]);
            }
        }
    }
    __syncthreads();
    if (threadIdx.x < 128) {
        atomicAdd(&colsum[threadIdx.x], cs1[threadIdx.x]);
        atomicAdd(&colsumsq[threadIdx.x], cs2[threadIdx.x]);
    }
}

// ---------------- K6: BN apply + unpermute to natural cols -----------------
__global__ void k_bn(float* __restrict__ h, const float* __restrict__ colsum,
                     const float* __restrict__ colsumsq, const float* __restrict__ gamma,
                     const float* __restrict__ beta) {
    __shared__ float sc[128], sh[128], tile[8][128];
    int t = threadIdx.x;
    if (t < 128) {
        int n = unperm(t);
        float m = colsum[t] * (1.f / N_NODES);
        float var = colsumsq[t] * (1.f / N_NODES) - m * m;
        float s = gamma[n] * rsqrtf(var + 1e-5f);
        sc[t] = s;
        sh[t] = beta[n] - m * s;
    }
    __syncthreads();
    int r = t >> 5;
    int p0 = (t & 31) * 4;
    int n0 = (p0 & 64) + ((p0 >> 2) & 15);
    for (int row0 = blockIdx.x * 8; row0 < N_NODES; row0 += gridDim.x * 8) {
        int row = row0 + r;
        float4 v = make_float4(0.f, 0.f, 0.f, 0.f);
        if (row < N_NODES) v = *reinterpret_cast<float4*>(h + (size_t)row * 128 + p0);
        v.x = v.x * sc[p0] + sh[p0];
        v.y = v.y * sc[p0 + 1] + sh[p0 + 1];
        v.z = v.z * sc[p0 + 2] + sh[p0 + 2];
        v.w = v.w * sc[p0 + 3] + sh[p0 + 3];
        tile[r][n0]      = v.x;
        tile[r][n0 + 16] = v.y;
        tile[r][n0 + 32] = v.z;
        tile[r][n0 + 48] = v.w;
        __syncthreads();
        if (row < N_NODES)
            *reinterpret_cast<float4*>(h + (size_t)row * 128 + p0) =
                *reinterpret_cast<float4*>(&tile[r][p0]);
        __syncthreads();
    }
}

extern "C" void kernel_launch(void* const* d_in, const int* in_sizes, int n_in,
                              void* d_out, int out_size, void* d_ws, size_t ws_size,
                              hipStream_t stream) {
    (void)in_sizes; (void)n_in; (void)out_size; (void)ws_size;
    const float* node_feats = (const float*)d_in[0];
    const int* src    = (const int*)d_in[1];
    const int* dst    = (const int*)d_in[2];
    const int* etype  = (const int*)d_in[3];
    const float* norm = (const float*)d_in[4];
    const float* basis = (const float*)d_in[5];
    const float* comp  = (const float*)d_in[6];
    const float* h_bias = (const float*)d_in[7];
    const float* W_res  = (const float*)d_in[8];
    const float* b_res  = (const float*)d_in[9];
    const float* gamma  = (const float*)d_in[10];
    const float* beta   = (const float*)d_in[11];

    char* ws = (char*)d_ws;
    int* ghist      = (int*)(ws + 0);
    int* cnt        = (int*)(ws + 1024);
    int* ntiles_p   = (int*)(ws + 2048);
    float* colsum   = (float*)(ws + 2560);
    float* colsumsq = (float*)(ws + 3072);
    int* gh2        = (int*)(ws + 8192);       // 80000 -> 88192
    int* tile_rel   = (int*)(ws + 88192);      // 40960
    int* tile_start = (int*)(ws + 129152);     // 40960
    int* tile_len   = (int*)(ws + 170112);     // 40960 -> 211072
    unsigned short* Wt      = (unsigned short*)(ws + 211072);    // 2129920 -> 2340992
    unsigned short* Wrest   = (unsigned short*)(ws + 2340992);   // 32768   -> 2373760
    unsigned short* node_bf = (unsigned short*)(ws + 2373760);   // 5120000 -> 7493760
    int* srcp       = (int*)(ws + 7493760);    // 2560000 -> 10053760
    float* normp    = (float*)(ws + 10053760); // 2560000 -> 12613760
    int* eidx       = (int*)(ws + 12613760);   // 2560000 -> 15173760
    float* resid    = (float*)(ws + 15173760); // 10240000 -> 25413760
    int* seg        = (int*)(ws + 25413760);   // 80004 -> 25493764, pad
    int* cnt2       = (int*)(ws + 25493776);   // 80000 -> 25573776
    const long T_BASE = 25573776L;             // 16B aligned
    float* W32      = (float*)(ws + T_BASE);   // aliased: dead before conv
    unsigned short* t_buf = (unsigned short*)(ws + T_BASE);      // 163.84 MB
    float* hacc = (float*)d_out;

    hipMemsetAsync(ws, 0, 88192, stream);
    k_prep1<<<3332, 256, 0, stream>>>(comp, basis, W32, etype, dst, ghist, gh2,
                                      node_feats, node_bf);
    k_prep3<<<345, 256, 0, stream>>>(gh2, cnt2, seg, ghist, cnt, ntiles_p,
                                     tile_rel, tile_start, tile_len,
                                     W32, Wt, W_res, Wrest);
    k_scatter2<<<(E_EDGES + SCAT_CH - 1) / SCAT_CH, 256, 0, stream>>>(
        etype, src, dst, norm, cnt, cnt2, srcp, normp, eidx);
    k_conv_gemm<<<NB_RESID + MAX_TILES, 256, 0, stream>>>(
        tile_rel, tile_start, tile_len, ntiles_p, srcp, normp, node_bf,
        Wt, Wrest, b_res, t_buf, resid);
    k_reduce_fused<<<N_NODES / 8, 256, 0, stream>>>(t_buf, seg, eidx, resid,
                                                    h_bias, hacc, colsum, colsumsq);
    k_bn<<<2500, 256, 0, stream>>>(hacc, colsum, colsumsq, gamma, beta);
}